// Round 1
// baseline (946.467 us; speedup 1.0000x reference)
//
#include <hip/hip_runtime.h>
#include <math.h>

#define LRELU_SLOPE 0.2f

// ---------------- CSR build ----------------

__global__ __launch_bounds__(256) void k_init_deg(int* __restrict__ deg, int n) {
    int i = blockIdx.x * 256 + threadIdx.x;
    if (i < n) deg[i] = 1;  // self loop contributes 1
}

__global__ __launch_bounds__(256) void k_count(const int* __restrict__ dst, int E, int* __restrict__ deg) {
    int i = blockIdx.x * 256 + threadIdx.x;
    if (i < E) atomicAdd(&deg[dst[i]], 1);
}

__global__ __launch_bounds__(1024) void k_scan1(const int* __restrict__ deg, int n,
                                                int* __restrict__ incl, int* __restrict__ partials) {
    __shared__ int tmp[1024];
    int i = blockIdx.x * 1024 + threadIdx.x;
    tmp[threadIdx.x] = (i < n) ? deg[i] : 0;
    __syncthreads();
    for (int off = 1; off < 1024; off <<= 1) {
        int t = (threadIdx.x >= off) ? tmp[threadIdx.x - off] : 0;
        __syncthreads();
        tmp[threadIdx.x] += t;
        __syncthreads();
    }
    if (i < n) incl[i] = tmp[threadIdx.x];
    if (threadIdx.x == 1023) partials[blockIdx.x] = tmp[1023];
}

__global__ void k_scan2(int* __restrict__ partials, int nb) {
    if (threadIdx.x == 0 && blockIdx.x == 0) {
        int run = 0;
        for (int i = 0; i < nb; i++) { int v = partials[i]; partials[i] = run; run += v; }
    }
}

__global__ __launch_bounds__(1024) void k_scan3(const int* __restrict__ incl, const int* __restrict__ partials,
                                                int n, int* __restrict__ rowstart) {
    int i = blockIdx.x * 1024 + threadIdx.x;
    if (i < n) rowstart[i + 1] = incl[i] + partials[blockIdx.x];
    if (i == 0) rowstart[0] = 0;
}

__global__ __launch_bounds__(256) void k_fill_self(const int* __restrict__ rowstart, int n,
                                                   int* __restrict__ csr, int* __restrict__ cursor) {
    int i = blockIdx.x * 256 + threadIdx.x;
    if (i < n) { csr[rowstart[i]] = i; cursor[i] = 1; }
}

__global__ __launch_bounds__(256) void k_fill(const int* __restrict__ src, const int* __restrict__ dst, int E,
                                              const int* __restrict__ rowstart, int* __restrict__ cursor,
                                              int* __restrict__ csr) {
    int i = blockIdx.x * 256 + threadIdx.x;
    if (i < E) {
        int d = dst[i];
        int p = rowstart[d] + atomicAdd(&cursor[d], 1);
        csr[p] = src[i];
    }
}

// ---------------- GEMM: out[n,COUT] = in[n,CIN] @ W[CIN,COUT] ----------------

template <int CIN, int COUT>
__global__ __launch_bounds__(256) void k_gemm(const float* __restrict__ in, const float* __restrict__ W,
                                              float* __restrict__ out, int n) {
    constexpr int RPB = 256 / COUT;
    __shared__ float Wl[CIN * COUT];
    __shared__ float Xl[RPB * CIN];
    for (int i = threadIdx.x; i < CIN * COUT; i += 256) Wl[i] = W[i];
    int row0 = blockIdx.x * RPB;
    for (int i = threadIdx.x; i < RPB * CIN; i += 256) {
        int r = row0 + i / CIN;
        Xl[i] = (r < n) ? in[(size_t)r * CIN + (i % CIN)] : 0.f;
    }
    __syncthreads();
    int lr = threadIdx.x / COUT;
    int col = threadIdx.x % COUT;
    float acc = 0.f;
#pragma unroll 8
    for (int k = 0; k < CIN; k++) acc = fmaf(Xl[lr * CIN + k], Wl[k * COUT + col], acc);
    int row = row0 + lr;
    if (row < n) out[(size_t)row * COUT + col] = acc;
}

// ---------------- attention coefficients: es = h @ a_s, ed = h @ a_d ----------------

template <int COUT>
__global__ __launch_bounds__(256) void k_attn(const float* __restrict__ h, const float* __restrict__ as,
                                              const float* __restrict__ ad, float* __restrict__ es,
                                              float* __restrict__ ed, int n) {
    int wid = (blockIdx.x * 256 + threadIdx.x) >> 6;
    int lane = threadIdx.x & 63;
    if (wid >= n) return;
    float p1 = 0.f, p2 = 0.f;
#pragma unroll
    for (int j = 0; j < (COUT + 63) / 64; j++) {
        int c = lane + j * 64;
        if (c < COUT) {
            float v = h[(size_t)wid * COUT + c];
            p1 = fmaf(v, as[c], p1);
            p2 = fmaf(v, ad[c], p2);
        }
    }
#pragma unroll
    for (int off = 32; off >= 1; off >>= 1) {
        p1 += __shfl_xor(p1, off);
        p2 += __shfl_xor(p2, off);
    }
    if (lane == 0) { es[wid] = p1; ed[wid] = p2; }
}

// ---------------- aggregation: one wave per destination node, online softmax ----------------

template <int COUT>
__global__ __launch_bounds__(256) void k_agg(const float* __restrict__ h, const float* __restrict__ es,
                                             const float* __restrict__ ed, const int* __restrict__ rowstart,
                                             const int* __restrict__ csr, const float* __restrict__ bias,
                                             float* __restrict__ out, int n) {
    int wid = (blockIdx.x * 256 + threadIdx.x) >> 6;
    int lane = threadIdx.x & 63;
    if (wid >= n) return;
    constexpr int VPL = (COUT + 63) / 64;
    float acc[VPL];
#pragma unroll
    for (int j = 0; j < VPL; j++) acc[j] = 0.f;
    float m = -1e30f, s = 0.f;
    float edv = ed[wid];
    int e0 = rowstart[wid], e1 = rowstart[wid + 1];
    for (int ei = e0; ei < e1; ei++) {
        int srcn = csr[ei];
        float e = es[srcn] + edv;
        e = (e > 0.f) ? e : e * LRELU_SLOPE;
        float mn = fmaxf(m, e);
        float scale = expf(m - mn);   // first iter: expf(-huge) = 0
        float p = expf(e - mn);
        s = s * scale + p;
#pragma unroll
        for (int j = 0; j < VPL; j++) {
            int c = lane + j * 64;
            float hv = (c < COUT) ? h[(size_t)srcn * COUT + c] : 0.f;
            acc[j] = fmaf(acc[j], scale, p * hv);
        }
        m = mn;
    }
    float inv = 1.f / s;  // every node has a self loop, s > 0
#pragma unroll
    for (int j = 0; j < VPL; j++) {
        int c = lane + j * 64;
        if (c < COUT) {
            float v = fmaf(acc[j], inv, bias[c]);
            out[(size_t)wid * COUT + c] = fmaxf(v, 0.f);  // layer relu
        }
    }
}

// ---------------- final FC: out[n,40] = h[n,128] @ fcW[128,40] + fcb ----------------

__global__ __launch_bounds__(256) void k_fc(const float* __restrict__ h, const float* __restrict__ W,
                                            const float* __restrict__ bias, float* __restrict__ out, int n) {
    __shared__ float Wl[128 * 40];
    for (int i = threadIdx.x; i < 128 * 40; i += 256) Wl[i] = W[i];
    __syncthreads();
    int idx = blockIdx.x * 256 + threadIdx.x;
    if (idx >= n * 40) return;
    int row = idx / 40;
    int col = idx % 40;
    float acc = 0.f;
#pragma unroll 8
    for (int k = 0; k < 128; k++) acc = fmaf(h[(size_t)row * 128 + k], Wl[k * 40 + col], acc);
    out[idx] = acc + bias[col];
}

// ---------------- launch ----------------

extern "C" void kernel_launch(void* const* d_in, const int* in_sizes, int n_in,
                              void* d_out, int out_size, void* d_ws, size_t ws_size,
                              hipStream_t stream) {
    const float* x   = (const float*)d_in[0];
    const int*   ei  = (const int*)d_in[1];
    const float* W1  = (const float*)d_in[2];
    const float* a1s = (const float*)d_in[3];
    const float* a1d = (const float*)d_in[4];
    const float* b1  = (const float*)d_in[5];
    const float* W2  = (const float*)d_in[6];
    const float* a2s = (const float*)d_in[7];
    const float* a2d = (const float*)d_in[8];
    const float* b2  = (const float*)d_in[9];
    const float* W3  = (const float*)d_in[10];
    const float* a3s = (const float*)d_in[11];
    const float* a3d = (const float*)d_in[12];
    const float* b3  = (const float*)d_in[13];
    const float* W4  = (const float*)d_in[14];
    const float* a4s = (const float*)d_in[15];
    const float* a4d = (const float*)d_in[16];
    const float* b4  = (const float*)d_in[17];
    const float* fcW = (const float*)d_in[18];
    const float* fcb = (const float*)d_in[19];

    const int n = in_sizes[0] / 256;   // 50000
    const int E = in_sizes[1] / 2;     // 800000
    const int* src = ei;
    const int* dst = ei + E;

    char* p = (char*)d_ws;
    auto alloc = [&](size_t bytes) -> char* {
        char* r = p;
        p += (bytes + 255) & ~(size_t)255;
        return r;
    };
    int*   deg      = (int*)alloc((size_t)n * 4);
    int*   cursor   = (int*)alloc((size_t)n * 4);
    int*   rowstart = (int*)alloc((size_t)(n + 1) * 4);
    int*   incl     = (int*)alloc((size_t)n * 4);
    int*   partials = (int*)alloc(256 * 4);
    int*   csr      = (int*)alloc((size_t)(E + n) * 4);
    float* es       = (float*)alloc((size_t)n * 4);
    float* ed       = (float*)alloc((size_t)n * 4);
    float* hA       = (float*)alloc((size_t)n * 128 * 4);
    float* hB       = (float*)alloc((size_t)n * 128 * 4);

    const int nb = (n + 1023) / 1024;

    k_init_deg<<<(n + 255) / 256, 256, 0, stream>>>(deg, n);
    k_count<<<(E + 255) / 256, 256, 0, stream>>>(dst, E, deg);
    k_scan1<<<nb, 1024, 0, stream>>>(deg, n, incl, partials);
    k_scan2<<<1, 64, 0, stream>>>(partials, nb);
    k_scan3<<<nb, 1024, 0, stream>>>(incl, partials, n, rowstart);
    k_fill_self<<<(n + 255) / 256, 256, 0, stream>>>(rowstart, n, csr, cursor);
    k_fill<<<(E + 255) / 256, 256, 0, stream>>>(src, dst, E, rowstart, cursor, csr);

    // layer 1: 256 -> 32
    k_gemm<256, 32><<<(n + 7) / 8, 256, 0, stream>>>(x, W1, hA, n);
    k_attn<32><<<(n + 3) / 4, 256, 0, stream>>>(hA, a1s, a1d, es, ed, n);
    k_agg<32><<<(n + 3) / 4, 256, 0, stream>>>(hA, es, ed, rowstart, csr, b1, hB, n);
    // layer 2: 32 -> 64
    k_gemm<32, 64><<<(n + 3) / 4, 256, 0, stream>>>(hB, W2, hA, n);
    k_attn<64><<<(n + 3) / 4, 256, 0, stream>>>(hA, a2s, a2d, es, ed, n);
    k_agg<64><<<(n + 3) / 4, 256, 0, stream>>>(hA, es, ed, rowstart, csr, b2, hB, n);
    // layer 3: 64 -> 128
    k_gemm<64, 128><<<(n + 1) / 2, 256, 0, stream>>>(hB, W3, hA, n);
    k_attn<128><<<(n + 3) / 4, 256, 0, stream>>>(hA, a3s, a3d, es, ed, n);
    k_agg<128><<<(n + 3) / 4, 256, 0, stream>>>(hA, es, ed, rowstart, csr, b3, hB, n);
    // layer 4: 128 -> 128
    k_gemm<128, 128><<<(n + 1) / 2, 256, 0, stream>>>(hB, W4, hA, n);
    k_attn<128><<<(n + 3) / 4, 256, 0, stream>>>(hA, a4s, a4d, es, ed, n);
    k_agg<128><<<(n + 3) / 4, 256, 0, stream>>>(hA, es, ed, rowstart, csr, b4, hB, n);
    // final FC: 128 -> 40
    k_fc<<<((size_t)n * 40 + 255) / 256, 256, 0, stream>>>(hB, fcW, fcb, (float*)d_out, n);
}

// Round 3
// 749.619 us; speedup vs baseline: 1.2626x; 1.2626x over previous
//
#include <hip/hip_runtime.h>
#include <math.h>

#define LRELU_SLOPE 0.2f

// ---------------- CSR build ----------------

__global__ __launch_bounds__(256) void k_init_deg(int* __restrict__ deg, int n) {
    int i = blockIdx.x * 256 + threadIdx.x;
    if (i < n) deg[i] = 1;  // self loop contributes 1
}

__global__ __launch_bounds__(256) void k_count(const int* __restrict__ dst, int E, int* __restrict__ deg) {
    int i = blockIdx.x * 256 + threadIdx.x;
    if (i < E) atomicAdd(&deg[dst[i]], 1);
}

__global__ __launch_bounds__(1024) void k_scan1(const int* __restrict__ deg, int n,
                                                int* __restrict__ incl, int* __restrict__ partials) {
    __shared__ int tmp[1024];
    int i = blockIdx.x * 1024 + threadIdx.x;
    tmp[threadIdx.x] = (i < n) ? deg[i] : 0;
    __syncthreads();
    for (int off = 1; off < 1024; off <<= 1) {
        int t = (threadIdx.x >= off) ? tmp[threadIdx.x - off] : 0;
        __syncthreads();
        tmp[threadIdx.x] += t;
        __syncthreads();
    }
    if (i < n) incl[i] = tmp[threadIdx.x];
    if (threadIdx.x == 1023) partials[blockIdx.x] = tmp[1023];
}

__global__ void k_scan2(int* __restrict__ partials, int nb) {
    if (threadIdx.x == 0 && blockIdx.x == 0) {
        int run = 0;
        for (int i = 0; i < nb; i++) { int v = partials[i]; partials[i] = run; run += v; }
    }
}

__global__ __launch_bounds__(1024) void k_scan3(const int* __restrict__ incl, const int* __restrict__ partials,
                                                int n, int* __restrict__ rowstart) {
    int i = blockIdx.x * 1024 + threadIdx.x;
    if (i < n) rowstart[i + 1] = incl[i] + partials[blockIdx.x];
    if (i == 0) rowstart[0] = 0;
}

__global__ __launch_bounds__(256) void k_fill_self(const int* __restrict__ rowstart, int n,
                                                   int* __restrict__ csr, int* __restrict__ cursor) {
    int i = blockIdx.x * 256 + threadIdx.x;
    if (i < n) { csr[rowstart[i]] = i; cursor[i] = 1; }
}

__global__ __launch_bounds__(256) void k_fill(const int* __restrict__ src, const int* __restrict__ dst, int E,
                                              const int* __restrict__ rowstart, int* __restrict__ cursor,
                                              int* __restrict__ csr) {
    int i = blockIdx.x * 256 + threadIdx.x;
    if (i < E) {
        int d = dst[i];
        int p = rowstart[d] + atomicAdd(&cursor[d], 1);
        csr[p] = src[i];
    }
}

// ---------------- register-tiled GEMM: out[n,COUT] = in[n,CIN] @ W[CIN,COUT] ----------------
// 256 threads; thread computes TM x TN outputs; X tile stored transposed in LDS.

template <int CIN, int COUT, int MT, int TM, int TN>
__global__ __launch_bounds__(256) void k_gemm_tiled(const float* __restrict__ in, const float* __restrict__ W,
                                                    float* __restrict__ out, int n) {
    constexpr int KB = 32;
    constexpr int NCT = COUT / TN;  // threads along columns
    constexpr int NRT = MT / TM;    // threads along rows
    static_assert(NCT * NRT == 256, "thread tiling must cover 256 threads");
    static_assert(CIN % KB == 0, "K must be multiple of KB");
    __shared__ __align__(16) float Xl[KB][MT + 4];   // transposed, padded
    __shared__ __align__(16) float Wl[KB][COUT];

    const int tid = threadIdx.x;
    const int tcol = tid % NCT;
    const int trow = tid / NCT;
    const int row0 = blockIdx.x * MT;

    float acc[TM][TN];
#pragma unroll
    for (int i = 0; i < TM; i++)
#pragma unroll
        for (int j = 0; j < TN; j++) acc[i][j] = 0.f;

    for (int k0 = 0; k0 < CIN; k0 += KB) {
        // --- load X tile (MT x KB), store transposed ---
        constexpr int F4PT = MT * KB / 4 / 256;   // float4s per thread
#pragma unroll
        for (int it = 0; it < F4PT; ++it) {
            int idx = tid + it * 256;
            int r = idx / (KB / 4);
            int c4 = idx % (KB / 4);
            float4 v = make_float4(0.f, 0.f, 0.f, 0.f);
            int gr = row0 + r;
            if (gr < n) v = *(const float4*)&in[(size_t)gr * CIN + k0 + c4 * 4];
            Xl[c4 * 4 + 0][r] = v.x;
            Xl[c4 * 4 + 1][r] = v.y;
            Xl[c4 * 4 + 2][r] = v.z;
            Xl[c4 * 4 + 3][r] = v.w;
        }
        // --- load W tile (KB x COUT, contiguous rows of W) ---
        constexpr int WF4 = KB * COUT / 4;
#pragma unroll
        for (int idx = tid; idx < WF4; idx += 256) {
            ((float4*)&Wl[0][0])[idx] = ((const float4*)&W[(size_t)k0 * COUT])[idx];
        }
        __syncthreads();

#pragma unroll
        for (int kk = 0; kk < KB; ++kk) {
            float xf[TM], wf[TN];
#pragma unroll
            for (int i = 0; i < TM; i += 4) {
                float4 v = *(const float4*)&Xl[kk][trow * TM + i];
                xf[i] = v.x; xf[i + 1] = v.y; xf[i + 2] = v.z; xf[i + 3] = v.w;
            }
#pragma unroll
            for (int j = 0; j < TN; j += 4) {
                float4 v = *(const float4*)&Wl[kk][tcol * TN + j];
                wf[j] = v.x; wf[j + 1] = v.y; wf[j + 2] = v.z; wf[j + 3] = v.w;
            }
#pragma unroll
            for (int i = 0; i < TM; i++)
#pragma unroll
                for (int j = 0; j < TN; j++) acc[i][j] = fmaf(xf[i], wf[j], acc[i][j]);
        }
        __syncthreads();
    }

#pragma unroll
    for (int i = 0; i < TM; i++) {
        int gr = row0 + trow * TM + i;
        if (gr < n) {
#pragma unroll
            for (int j = 0; j < TN; j += 4) {
                float4 v = make_float4(acc[i][j], acc[i][j + 1], acc[i][j + 2], acc[i][j + 3]);
                *(float4*)&out[(size_t)gr * COUT + tcol * TN + j] = v;
            }
        }
    }
}

// ---------------- attention coefficients: es = h @ a_s, ed = h @ a_d ----------------

template <int COUT>
__global__ __launch_bounds__(256) void k_attn(const float* __restrict__ h, const float* __restrict__ as,
                                              const float* __restrict__ ad, float* __restrict__ es,
                                              float* __restrict__ ed, int n) {
    int wid = (blockIdx.x * 256 + threadIdx.x) >> 6;
    int lane = threadIdx.x & 63;
    if (wid >= n) return;
    float p1 = 0.f, p2 = 0.f;
#pragma unroll
    for (int j = 0; j < (COUT + 63) / 64; j++) {
        int c = lane + j * 64;
        if (c < COUT) {
            float v = h[(size_t)wid * COUT + c];
            p1 = fmaf(v, as[c], p1);
            p2 = fmaf(v, ad[c], p2);
        }
    }
#pragma unroll
    for (int off = 32; off >= 1; off >>= 1) {
        p1 += __shfl_xor(p1, off);
        p2 += __shfl_xor(p2, off);
    }
    if (lane == 0) { es[wid] = p1; ed[wid] = p2; }
}

// ---------------- aggregation: one wave per destination node, online softmax ----------------

template <int COUT>
__global__ __launch_bounds__(256) void k_agg(const float* __restrict__ h, const float* __restrict__ es,
                                             const float* __restrict__ ed, const int* __restrict__ rowstart,
                                             const int* __restrict__ csr, const float* __restrict__ bias,
                                             float* __restrict__ out, int n) {
    int wid = (blockIdx.x * 256 + threadIdx.x) >> 6;
    int lane = threadIdx.x & 63;
    if (wid >= n) return;
    constexpr int VPL = (COUT + 63) / 64;
    float acc[VPL];
#pragma unroll
    for (int j = 0; j < VPL; j++) acc[j] = 0.f;
    float m = -1e30f, s = 0.f;
    float edv = ed[wid];
    int e0 = rowstart[wid], e1 = rowstart[wid + 1];
    for (int ei = e0; ei < e1; ei++) {
        int srcn = csr[ei];
        float e = es[srcn] + edv;
        e = (e > 0.f) ? e : e * LRELU_SLOPE;
        float mn = fmaxf(m, e);
        float scale = expf(m - mn);   // first iter: expf(-huge) = 0
        float p = expf(e - mn);
        s = s * scale + p;
#pragma unroll
        for (int j = 0; j < VPL; j++) {
            int c = lane + j * 64;
            float hv = (c < COUT) ? h[(size_t)srcn * COUT + c] : 0.f;
            acc[j] = fmaf(acc[j], scale, p * hv);
        }
        m = mn;
    }
    float inv = 1.f / s;  // every node has a self loop, s > 0
#pragma unroll
    for (int j = 0; j < VPL; j++) {
        int c = lane + j * 64;
        if (c < COUT) {
            float v = fmaf(acc[j], inv, bias[c]);
            out[(size_t)wid * COUT + c] = fmaxf(v, 0.f);  // layer relu
        }
    }
}

// ---------------- final FC: out[n,40] = h[n,128] @ fcW[128,40] + fcb ----------------

__global__ __launch_bounds__(256) void k_fc(const float* __restrict__ h, const float* __restrict__ W,
                                            const float* __restrict__ bias, float* __restrict__ out, int n) {
    __shared__ float Wl[128 * 40];
    for (int i = threadIdx.x; i < 128 * 40; i += 256) Wl[i] = W[i];
    __syncthreads();
    int idx = blockIdx.x * 256 + threadIdx.x;
    if (idx >= n * 40) return;
    int row = idx / 40;
    int col = idx % 40;
    float acc = 0.f;
#pragma unroll 8
    for (int k = 0; k < 128; k++) acc = fmaf(h[(size_t)row * 128 + k], Wl[k * 40 + col], acc);
    out[idx] = acc + bias[col];
}

// ---------------- launch ----------------

extern "C" void kernel_launch(void* const* d_in, const int* in_sizes, int n_in,
                              void* d_out, int out_size, void* d_ws, size_t ws_size,
                              hipStream_t stream) {
    const float* x   = (const float*)d_in[0];
    const int*   ei  = (const int*)d_in[1];
    const float* W1  = (const float*)d_in[2];
    const float* a1s = (const float*)d_in[3];
    const float* a1d = (const float*)d_in[4];
    const float* b1  = (const float*)d_in[5];
    const float* W2  = (const float*)d_in[6];
    const float* a2s = (const float*)d_in[7];
    const float* a2d = (const float*)d_in[8];
    const float* b2  = (const float*)d_in[9];
    const float* W3  = (const float*)d_in[10];
    const float* a3s = (const float*)d_in[11];
    const float* a3d = (const float*)d_in[12];
    const float* b3  = (const float*)d_in[13];
    const float* W4  = (const float*)d_in[14];
    const float* a4s = (const float*)d_in[15];
    const float* a4d = (const float*)d_in[16];
    const float* b4  = (const float*)d_in[17];
    const float* fcW = (const float*)d_in[18];
    const float* fcb = (const float*)d_in[19];

    const int n = in_sizes[0] / 256;   // 50000
    const int E = in_sizes[1] / 2;     // 800000
    const int* src = ei;
    const int* dst = ei + E;

    char* p = (char*)d_ws;
    auto alloc = [&](size_t bytes) -> char* {
        char* r = p;
        p += (bytes + 255) & ~(size_t)255;
        return r;
    };
    int*   deg      = (int*)alloc((size_t)n * 4);
    int*   cursor   = (int*)alloc((size_t)n * 4);
    int*   rowstart = (int*)alloc((size_t)(n + 1) * 4);
    int*   incl     = (int*)alloc((size_t)n * 4);
    int*   partials = (int*)alloc(256 * 4);
    int*   csr      = (int*)alloc((size_t)(E + n) * 4);
    float* es       = (float*)alloc((size_t)n * 4);
    float* ed       = (float*)alloc((size_t)n * 4);
    float* hA       = (float*)alloc((size_t)n * 128 * 4);
    float* hB       = (float*)alloc((size_t)n * 128 * 4);

    const int nb = (n + 1023) / 1024;

    k_init_deg<<<(n + 255) / 256, 256, 0, stream>>>(deg, n);
    k_count<<<(E + 255) / 256, 256, 0, stream>>>(dst, E, deg);
    k_scan1<<<nb, 1024, 0, stream>>>(deg, n, incl, partials);
    k_scan2<<<1, 64, 0, stream>>>(partials, nb);
    k_scan3<<<nb, 1024, 0, stream>>>(incl, partials, n, rowstart);
    k_fill_self<<<(n + 255) / 256, 256, 0, stream>>>(rowstart, n, csr, cursor);
    k_fill<<<(E + 255) / 256, 256, 0, stream>>>(src, dst, E, rowstart, cursor, csr);

    // layer 1: 256 -> 32   (MT=128, TM=4, TN=4 -> 32x8 threads)
    k_gemm_tiled<256, 32, 128, 4, 4><<<(n + 127) / 128, 256, 0, stream>>>(x, W1, hA, n);
    k_attn<32><<<(n + 3) / 4, 256, 0, stream>>>(hA, a1s, a1d, es, ed, n);
    k_agg<32><<<(n + 3) / 4, 256, 0, stream>>>(hA, es, ed, rowstart, csr, b1, hB, n);
    // layer 2: 32 -> 64    (MT=64, TM=4, TN=4 -> 16x16 threads)
    k_gemm_tiled<32, 64, 64, 4, 4><<<(n + 63) / 64, 256, 0, stream>>>(hB, W2, hA, n);
    k_attn<64><<<(n + 3) / 4, 256, 0, stream>>>(hA, a2s, a2d, es, ed, n);
    k_agg<64><<<(n + 3) / 4, 256, 0, stream>>>(hA, es, ed, rowstart, csr, b2, hB, n);
    // layer 3: 64 -> 128   (MT=64, TM=4, TN=8 -> 16x16 threads)
    k_gemm_tiled<64, 128, 64, 4, 8><<<(n + 63) / 64, 256, 0, stream>>>(hB, W3, hA, n);
    k_attn<128><<<(n + 3) / 4, 256, 0, stream>>>(hA, a3s, a3d, es, ed, n);
    k_agg<128><<<(n + 3) / 4, 256, 0, stream>>>(hA, es, ed, rowstart, csr, b3, hB, n);
    // layer 4: 128 -> 128  (MT=64, TM=4, TN=8)
    k_gemm_tiled<128, 128, 64, 4, 8><<<(n + 63) / 64, 256, 0, stream>>>(hB, W4, hA, n);
    k_attn<128><<<(n + 3) / 4, 256, 0, stream>>>(hA, a4s, a4d, es, ed, n);
    k_agg<128><<<(n + 3) / 4, 256, 0, stream>>>(hA, es, ed, rowstart, csr, b4, hB, n);
    // final FC: 128 -> 40
    k_fc<<<((size_t)n * 40 + 255) / 256, 256, 0, stream>>>(hB, fcW, fcb, (float*)d_out, n);
}

// Round 7
// 639.737 us; speedup vs baseline: 1.4795x; 1.1718x over previous
//
#include <hip/hip_runtime.h>
#include <math.h>

#define LRELU_SLOPE 0.2f

// ---------------- CSR build ----------------

__global__ __launch_bounds__(256) void k_init_deg(int* __restrict__ deg, int n) {
    int i = blockIdx.x * 256 + threadIdx.x;
    if (i < n) deg[i] = 1;  // self loop contributes 1
}

__global__ __launch_bounds__(256) void k_count(const int* __restrict__ dst, int E, int* __restrict__ deg) {
    int i = blockIdx.x * 256 + threadIdx.x;
    if (i < E) atomicAdd(&deg[dst[i]], 1);
}

__global__ __launch_bounds__(1024) void k_scan1(const int* __restrict__ deg, int n,
                                                int* __restrict__ incl, int* __restrict__ partials) {
    __shared__ int tmp[1024];
    int i = blockIdx.x * 1024 + threadIdx.x;
    tmp[threadIdx.x] = (i < n) ? deg[i] : 0;
    __syncthreads();
    for (int off = 1; off < 1024; off <<= 1) {
        int t = (threadIdx.x >= off) ? tmp[threadIdx.x - off] : 0;
        __syncthreads();
        tmp[threadIdx.x] += t;
        __syncthreads();
    }
    if (i < n) incl[i] = tmp[threadIdx.x];
    if (threadIdx.x == 1023) partials[blockIdx.x] = tmp[1023];
}

__global__ void k_scan2(int* __restrict__ partials, int nb) {
    if (threadIdx.x == 0 && blockIdx.x == 0) {
        int run = 0;
        for (int i = 0; i < nb; i++) { int v = partials[i]; partials[i] = run; run += v; }
    }
}

__global__ __launch_bounds__(1024) void k_scan3(const int* __restrict__ incl, const int* __restrict__ partials,
                                                int n, int* __restrict__ rowstart) {
    int i = blockIdx.x * 1024 + threadIdx.x;
    if (i < n) rowstart[i + 1] = incl[i] + partials[blockIdx.x];
    if (i == 0) rowstart[0] = 0;
}

__global__ __launch_bounds__(256) void k_fill_self(const int* __restrict__ rowstart, int n,
                                                   int* __restrict__ csr, int* __restrict__ cursor) {
    int i = blockIdx.x * 256 + threadIdx.x;
    if (i < n) { csr[rowstart[i]] = i; cursor[i] = 1; }
}

__global__ __launch_bounds__(256) void k_fill(const int* __restrict__ src, const int* __restrict__ dst, int E,
                                              const int* __restrict__ rowstart, int* __restrict__ cursor,
                                              int* __restrict__ csr) {
    int i = blockIdx.x * 256 + threadIdx.x;
    if (i < E) {
        int d = dst[i];
        int p = rowstart[d] + atomicAdd(&cursor[d], 1);
        csr[p] = src[i];
    }
}

// ---------------- register-tiled GEMM: out[n,COUT] = in[n,CIN] @ W[CIN,COUT] ----------------

template <int CIN, int COUT, int MT, int TM, int TN>
__global__ __launch_bounds__(256) void k_gemm_tiled(const float* __restrict__ in, const float* __restrict__ W,
                                                    float* __restrict__ out, int n) {
    constexpr int KB = 32;
    constexpr int NCT = COUT / TN;
    constexpr int NRT = MT / TM;
    static_assert(NCT * NRT == 256, "thread tiling must cover 256 threads");
    static_assert(CIN % KB == 0, "K must be multiple of KB");
    __shared__ __align__(16) float Xl[KB][MT + 4];
    __shared__ __align__(16) float Wl[KB][COUT];

    const int tid = threadIdx.x;
    const int tcol = tid % NCT;
    const int trow = tid / NCT;
    const int row0 = blockIdx.x * MT;

    float acc[TM][TN];
#pragma unroll
    for (int i = 0; i < TM; i++)
#pragma unroll
        for (int j = 0; j < TN; j++) acc[i][j] = 0.f;

    for (int k0 = 0; k0 < CIN; k0 += KB) {
        constexpr int F4PT = MT * KB / 4 / 256;
#pragma unroll
        for (int it = 0; it < F4PT; ++it) {
            int idx = tid + it * 256;
            int r = idx / (KB / 4);
            int c4 = idx % (KB / 4);
            float4 v = make_float4(0.f, 0.f, 0.f, 0.f);
            int gr = row0 + r;
            if (gr < n) v = *(const float4*)&in[(size_t)gr * CIN + k0 + c4 * 4];
            Xl[c4 * 4 + 0][r] = v.x;
            Xl[c4 * 4 + 1][r] = v.y;
            Xl[c4 * 4 + 2][r] = v.z;
            Xl[c4 * 4 + 3][r] = v.w;
        }
        constexpr int WF4 = KB * COUT / 4;
#pragma unroll
        for (int idx = tid; idx < WF4; idx += 256) {
            ((float4*)&Wl[0][0])[idx] = ((const float4*)&W[(size_t)k0 * COUT])[idx];
        }
        __syncthreads();

#pragma unroll
        for (int kk = 0; kk < KB; ++kk) {
            float xf[TM], wf[TN];
#pragma unroll
            for (int i = 0; i < TM; i += 4) {
                float4 v = *(const float4*)&Xl[kk][trow * TM + i];
                xf[i] = v.x; xf[i + 1] = v.y; xf[i + 2] = v.z; xf[i + 3] = v.w;
            }
#pragma unroll
            for (int j = 0; j < TN; j += 4) {
                float4 v = *(const float4*)&Wl[kk][tcol * TN + j];
                wf[j] = v.x; wf[j + 1] = v.y; wf[j + 2] = v.z; wf[j + 3] = v.w;
            }
#pragma unroll
            for (int i = 0; i < TM; i++)
#pragma unroll
                for (int j = 0; j < TN; j++) acc[i][j] = fmaf(xf[i], wf[j], acc[i][j]);
        }
        __syncthreads();
    }

#pragma unroll
    for (int i = 0; i < TM; i++) {
        int gr = row0 + trow * TM + i;
        if (gr < n) {
#pragma unroll
            for (int j = 0; j < TN; j += 4) {
                float4 v = make_float4(acc[i][j], acc[i][j + 1], acc[i][j + 2], acc[i][j + 3]);
                *(float4*)&out[(size_t)gr * COUT + tcol * TN + j] = v;
            }
        }
    }
}

// ---------------- attention coefficients: es = h @ a_s, ed = h @ a_d ----------------

template <int COUT>
__global__ __launch_bounds__(256) void k_attn(const float* __restrict__ h, const float* __restrict__ as,
                                              const float* __restrict__ ad, float* __restrict__ es,
                                              float* __restrict__ ed, int n) {
    int wid = (blockIdx.x * 256 + threadIdx.x) >> 6;
    int lane = threadIdx.x & 63;
    if (wid >= n) return;
    float p1 = 0.f, p2 = 0.f;
#pragma unroll
    for (int j = 0; j < (COUT + 63) / 64; j++) {
        int c = lane + j * 64;
        if (c < COUT) {
            float v = h[(size_t)wid * COUT + c];
            p1 = fmaf(v, as[c], p1);
            p2 = fmaf(v, ad[c], p2);
        }
    }
#pragma unroll
    for (int off = 32; off >= 1; off >>= 1) {
        p1 += __shfl_xor(p1, off);
        p2 += __shfl_xor(p2, off);
    }
    if (lane == 0) { es[wid] = p1; ed[wid] = p2; }
}

// ---------------- edge softmax: alpha[slot] for each CSR slot ----------------
// one wave per destination node, lanes parallel over its incoming edges

__global__ __launch_bounds__(256) void k_alpha(const float* __restrict__ es, const float* __restrict__ ed,
                                               const int* __restrict__ rowstart, const int* __restrict__ csr,
                                               float* __restrict__ alpha, int n) {
    int wid = (blockIdx.x * 256 + threadIdx.x) >> 6;
    int lane = threadIdx.x & 63;
    if (wid >= n) return;
    int e0 = rowstart[wid], e1 = rowstart[wid + 1];
    float edv = ed[wid];
    float m = -1e30f;
    for (int s = e0 + lane; s < e1; s += 64) {
        float ev = es[csr[s]] + edv;
        ev = (ev > 0.f) ? ev : ev * LRELU_SLOPE;
        m = fmaxf(m, ev);
    }
#pragma unroll
    for (int off = 32; off >= 1; off >>= 1) m = fmaxf(m, __shfl_xor(m, off));
    float sum = 0.f;
    for (int s = e0 + lane; s < e1; s += 64) {
        float ev = es[csr[s]] + edv;
        ev = (ev > 0.f) ? ev : ev * LRELU_SLOPE;
        sum += expf(ev - m);
    }
#pragma unroll
    for (int off = 32; off >= 1; off >>= 1) sum += __shfl_xor(sum, off);
    float inv = 1.f / sum;  // self loop guarantees sum > 0
    for (int s = e0 + lane; s < e1; s += 64) {
        float ev = es[csr[s]] + edv;
        ev = (ev > 0.f) ? ev : ev * LRELU_SLOPE;
        alpha[s] = expf(ev - m) * inv;
    }
}

// ---------------- weighted gather: out[d] = relu(sum_e alpha[e]*h[src[e]] + bias) ----------------
// wave per dst; COUT/4 lanes per edge (float4), 64/(COUT/4) edges per iteration

template <int COUT>
__global__ __launch_bounds__(256) void k_gather(const float* __restrict__ h, const float* __restrict__ alpha,
                                                const int* __restrict__ rowstart, const int* __restrict__ csr,
                                                const float* __restrict__ bias, float* __restrict__ out, int n) {
    constexpr int GSZ = COUT / 4;   // lanes per edge
    constexpr int NG = 64 / GSZ;    // edges per iteration
    int wid = (blockIdx.x * 256 + threadIdx.x) >> 6;
    int lane = threadIdx.x & 63;
    if (wid >= n) return;
    int e0 = rowstart[wid], e1 = rowstart[wid + 1];
    int g = lane / GSZ;
    int li = lane % GSZ;
    float acc0 = 0.f, acc1 = 0.f, acc2 = 0.f, acc3 = 0.f;
    for (int base = e0; base < e1; base += NG) {
        int slot = base + g;
        if (slot < e1) {
            int srcn = csr[slot];
            float a = alpha[slot];
            float4 v = *(const float4*)&h[(size_t)srcn * COUT + li * 4];
            acc0 = fmaf(a, v.x, acc0);
            acc1 = fmaf(a, v.y, acc1);
            acc2 = fmaf(a, v.z, acc2);
            acc3 = fmaf(a, v.w, acc3);
        }
    }
#pragma unroll
    for (int off = GSZ; off < 64; off <<= 1) {
        acc0 += __shfl_xor(acc0, off);
        acc1 += __shfl_xor(acc1, off);
        acc2 += __shfl_xor(acc2, off);
        acc3 += __shfl_xor(acc3, off);
    }
    if (lane < GSZ) {
        float4 bv = *(const float4*)&bias[lane * 4];
        float4 o;
        o.x = fmaxf(acc0 + bv.x, 0.f);
        o.y = fmaxf(acc1 + bv.y, 0.f);
        o.z = fmaxf(acc2 + bv.z, 0.f);
        o.w = fmaxf(acc3 + bv.w, 0.f);
        *(float4*)&out[(size_t)wid * COUT + lane * 4] = o;
    }
}

// ---------------- final FC: out[n,40] = h[n,128] @ fcW[128,40] + fcb ----------------

__global__ __launch_bounds__(256) void k_fc(const float* __restrict__ h, const float* __restrict__ W,
                                            const float* __restrict__ bias, float* __restrict__ out, int n) {
    __shared__ float Wl[128 * 40];
    for (int i = threadIdx.x; i < 128 * 40; i += 256) Wl[i] = W[i];
    __syncthreads();
    int idx = blockIdx.x * 256 + threadIdx.x;
    if (idx >= n * 40) return;
    int row = idx / 40;
    int col = idx % 40;
    float acc = 0.f;
#pragma unroll 8
    for (int k = 0; k < 128; k++) acc = fmaf(h[(size_t)row * 128 + k], Wl[k * 40 + col], acc);
    out[idx] = acc + bias[col];
}

// ---------------- launch ----------------

extern "C" void kernel_launch(void* const* d_in, const int* in_sizes, int n_in,
                              void* d_out, int out_size, void* d_ws, size_t ws_size,
                              hipStream_t stream) {
    const float* x   = (const float*)d_in[0];
    const int*   ei  = (const int*)d_in[1];
    const float* W1  = (const float*)d_in[2];
    const float* a1s = (const float*)d_in[3];
    const float* a1d = (const float*)d_in[4];
    const float* b1  = (const float*)d_in[5];
    const float* W2  = (const float*)d_in[6];
    const float* a2s = (const float*)d_in[7];
    const float* a2d = (const float*)d_in[8];
    const float* b2  = (const float*)d_in[9];
    const float* W3  = (const float*)d_in[10];
    const float* a3s = (const float*)d_in[11];
    const float* a3d = (const float*)d_in[12];
    const float* b3  = (const float*)d_in[13];
    const float* W4  = (const float*)d_in[14];
    const float* a4s = (const float*)d_in[15];
    const float* a4d = (const float*)d_in[16];
    const float* b4  = (const float*)d_in[17];
    const float* fcW = (const float*)d_in[18];
    const float* fcb = (const float*)d_in[19];

    const int n = in_sizes[0] / 256;   // 50000
    const int E = in_sizes[1] / 2;     // 800000
    const int* src = ei;
    const int* dst = ei + E;

    char* p = (char*)d_ws;
    auto alloc = [&](size_t bytes) -> char* {
        char* r = p;
        p += (bytes + 255) & ~(size_t)255;
        return r;
    };
    int*   deg      = (int*)alloc((size_t)n * 4);
    int*   cursor   = (int*)alloc((size_t)n * 4);
    int*   rowstart = (int*)alloc((size_t)(n + 1) * 4);
    int*   incl     = (int*)alloc((size_t)n * 4);
    int*   partials = (int*)alloc(256 * 4);
    int*   csr      = (int*)alloc((size_t)(E + n) * 4);
    float* alpha    = (float*)alloc((size_t)(E + n) * 4);
    float* es       = (float*)alloc((size_t)n * 4);
    float* ed       = (float*)alloc((size_t)n * 4);
    float* hA       = (float*)alloc((size_t)n * 128 * 4);
    float* hB       = (float*)alloc((size_t)n * 128 * 4);

    const int nb = (n + 1023) / 1024;

    k_init_deg<<<(n + 255) / 256, 256, 0, stream>>>(deg, n);
    k_count<<<(E + 255) / 256, 256, 0, stream>>>(dst, E, deg);
    k_scan1<<<nb, 1024, 0, stream>>>(deg, n, incl, partials);
    k_scan2<<<1, 64, 0, stream>>>(partials, nb);
    k_scan3<<<nb, 1024, 0, stream>>>(incl, partials, n, rowstart);
    k_fill_self<<<(n + 255) / 256, 256, 0, stream>>>(rowstart, n, csr, cursor);
    k_fill<<<(E + 255) / 256, 256, 0, stream>>>(src, dst, E, rowstart, cursor, csr);

    const int gw = (n + 3) / 4;  // blocks for wave-per-node kernels

    // layer 1: 256 -> 32
    k_gemm_tiled<256, 32, 128, 4, 4><<<(n + 127) / 128, 256, 0, stream>>>(x, W1, hA, n);
    k_attn<32><<<gw, 256, 0, stream>>>(hA, a1s, a1d, es, ed, n);
    k_alpha<<<gw, 256, 0, stream>>>(es, ed, rowstart, csr, alpha, n);
    k_gather<32><<<gw, 256, 0, stream>>>(hA, alpha, rowstart, csr, b1, hB, n);
    // layer 2: 32 -> 64
    k_gemm_tiled<32, 64, 64, 4, 4><<<(n + 63) / 64, 256, 0, stream>>>(hB, W2, hA, n);
    k_attn<64><<<gw, 256, 0, stream>>>(hA, a2s, a2d, es, ed, n);
    k_alpha<<<gw, 256, 0, stream>>>(es, ed, rowstart, csr, alpha, n);
    k_gather<64><<<gw, 256, 0, stream>>>(hA, alpha, rowstart, csr, b2, hB, n);
    // layer 3: 64 -> 128
    k_gemm_tiled<64, 128, 64, 4, 8><<<(n + 63) / 64, 256, 0, stream>>>(hB, W3, hA, n);
    k_attn<128><<<gw, 256, 0, stream>>>(hA, a3s, a3d, es, ed, n);
    k_alpha<<<gw, 256, 0, stream>>>(es, ed, rowstart, csr, alpha, n);
    k_gather<128><<<gw, 256, 0, stream>>>(hA, alpha, rowstart, csr, b3, hB, n);
    // layer 4: 128 -> 128
    k_gemm_tiled<128, 128, 64, 4, 8><<<(n + 63) / 64, 256, 0, stream>>>(hB, W4, hA, n);
    k_attn<128><<<gw, 256, 0, stream>>>(hA, a4s, a4d, es, ed, n);
    k_alpha<<<gw, 256, 0, stream>>>(es, ed, rowstart, csr, alpha, n);
    k_gather<128><<<gw, 256, 0, stream>>>(hA, alpha, rowstart, csr, b4, hB, n);
    // final FC: 128 -> 40
    k_fc<<<((size_t)n * 40 + 255) / 256, 256, 0, stream>>>(hB, fcW, fcb, (float*)d_out, n);
}

// Round 15
// 624.547 us; speedup vs baseline: 1.5154x; 1.0243x over previous
//
#include <hip/hip_runtime.h>
#include <math.h>

#define LRELU_SLOPE 0.2f

// ---------------- CSR build ----------------

__global__ __launch_bounds__(256) void k_init_deg(int* __restrict__ deg, int n) {
    int i = blockIdx.x * 256 + threadIdx.x;
    if (i < n) deg[i] = 1;  // self loop contributes 1
}

__global__ __launch_bounds__(256) void k_count(const int* __restrict__ dst, int E, int* __restrict__ deg) {
    int i = blockIdx.x * 256 + threadIdx.x;
    if (i < E) atomicAdd(&deg[dst[i]], 1);
}

__global__ __launch_bounds__(1024) void k_scan1(const int* __restrict__ deg, int n,
                                                int* __restrict__ incl, int* __restrict__ partials) {
    __shared__ int tmp[1024];
    int i = blockIdx.x * 1024 + threadIdx.x;
    tmp[threadIdx.x] = (i < n) ? deg[i] : 0;
    __syncthreads();
    for (int off = 1; off < 1024; off <<= 1) {
        int t = (threadIdx.x >= off) ? tmp[threadIdx.x - off] : 0;
        __syncthreads();
        tmp[threadIdx.x] += t;
        __syncthreads();
    }
    if (i < n) incl[i] = tmp[threadIdx.x];
    if (threadIdx.x == 1023) partials[blockIdx.x] = tmp[1023];
}

__global__ void k_scan2(int* __restrict__ partials, int nb) {
    if (threadIdx.x == 0 && blockIdx.x == 0) {
        int run = 0;
        for (int i = 0; i < nb; i++) { int v = partials[i]; partials[i] = run; run += v; }
    }
}

__global__ __launch_bounds__(1024) void k_scan3(const int* __restrict__ incl, const int* __restrict__ partials,
                                                int n, int* __restrict__ rowstart) {
    int i = blockIdx.x * 1024 + threadIdx.x;
    if (i < n) rowstart[i + 1] = incl[i] + partials[blockIdx.x];
    if (i == 0) rowstart[0] = 0;
}

__global__ __launch_bounds__(256) void k_fill_self(const int* __restrict__ rowstart, int n,
                                                   int* __restrict__ csr, int* __restrict__ cursor) {
    int i = blockIdx.x * 256 + threadIdx.x;
    if (i < n) { csr[rowstart[i]] = i; cursor[i] = 1; }
}

__global__ __launch_bounds__(256) void k_fill(const int* __restrict__ src, const int* __restrict__ dst, int E,
                                              const int* __restrict__ rowstart, int* __restrict__ cursor,
                                              int* __restrict__ csr) {
    int i = blockIdx.x * 256 + threadIdx.x;
    if (i < E) {
        int d = dst[i];
        int p = rowstart[d] + atomicAdd(&cursor[d], 1);
        csr[p] = src[i];
    }
}

// ---------------- register-tiled GEMM: out[n,COUT] = in[n,CIN] @ W[CIN,COUT] ----------------

template <int CIN, int COUT, int MT, int TM, int TN>
__global__ __launch_bounds__(256) void k_gemm_tiled(const float* __restrict__ in, const float* __restrict__ W,
                                                    float* __restrict__ out, int n) {
    constexpr int KB = 32;
    constexpr int NCT = COUT / TN;
    constexpr int NRT = MT / TM;
    static_assert(NCT * NRT == 256, "thread tiling must cover 256 threads");
    static_assert(CIN % KB == 0, "K must be multiple of KB");
    __shared__ __align__(16) float Xl[KB][MT + 4];
    __shared__ __align__(16) float Wl[KB][COUT];

    const int tid = threadIdx.x;
    const int tcol = tid % NCT;
    const int trow = tid / NCT;
    const int row0 = blockIdx.x * MT;

    float acc[TM][TN];
#pragma unroll
    for (int i = 0; i < TM; i++)
#pragma unroll
        for (int j = 0; j < TN; j++) acc[i][j] = 0.f;

    for (int k0 = 0; k0 < CIN; k0 += KB) {
        constexpr int F4PT = MT * KB / 4 / 256;
#pragma unroll
        for (int it = 0; it < F4PT; ++it) {
            int idx = tid + it * 256;
            int r = idx / (KB / 4);
            int c4 = idx % (KB / 4);
            float4 v = make_float4(0.f, 0.f, 0.f, 0.f);
            int gr = row0 + r;
            if (gr < n) v = *(const float4*)&in[(size_t)gr * CIN + k0 + c4 * 4];
            Xl[c4 * 4 + 0][r] = v.x;
            Xl[c4 * 4 + 1][r] = v.y;
            Xl[c4 * 4 + 2][r] = v.z;
            Xl[c4 * 4 + 3][r] = v.w;
        }
        constexpr int WF4 = KB * COUT / 4;
#pragma unroll
        for (int idx = tid; idx < WF4; idx += 256) {
            ((float4*)&Wl[0][0])[idx] = ((const float4*)&W[(size_t)k0 * COUT])[idx];
        }
        __syncthreads();

#pragma unroll
        for (int kk = 0; kk < KB; ++kk) {
            float xf[TM], wf[TN];
#pragma unroll
            for (int i = 0; i < TM; i += 4) {
                float4 v = *(const float4*)&Xl[kk][trow * TM + i];
                xf[i] = v.x; xf[i + 1] = v.y; xf[i + 2] = v.z; xf[i + 3] = v.w;
            }
#pragma unroll
            for (int j = 0; j < TN; j += 4) {
                float4 v = *(const float4*)&Wl[kk][tcol * TN + j];
                wf[j] = v.x; wf[j + 1] = v.y; wf[j + 2] = v.z; wf[j + 3] = v.w;
            }
#pragma unroll
            for (int i = 0; i < TM; i++)
#pragma unroll
                for (int j = 0; j < TN; j++) acc[i][j] = fmaf(xf[i], wf[j], acc[i][j]);
        }
        __syncthreads();
    }

#pragma unroll
    for (int i = 0; i < TM; i++) {
        int gr = row0 + trow * TM + i;
        if (gr < n) {
#pragma unroll
            for (int j = 0; j < TN; j += 4) {
                float4 v = make_float4(acc[i][j], acc[i][j + 1], acc[i][j + 2], acc[i][j + 3]);
                *(float4*)&out[(size_t)gr * COUT + tcol * TN + j] = v;
            }
        }
    }
}

// ---------------- attention coefficients: es = h @ a_s, ed = h @ a_d ----------------

template <int COUT>
__global__ __launch_bounds__(256) void k_attn(const float* __restrict__ h, const float* __restrict__ as,
                                              const float* __restrict__ ad, float* __restrict__ es,
                                              float* __restrict__ ed, int n) {
    int wid = (blockIdx.x * 256 + threadIdx.x) >> 6;
    int lane = threadIdx.x & 63;
    if (wid >= n) return;
    float p1 = 0.f, p2 = 0.f;
#pragma unroll
    for (int j = 0; j < (COUT + 63) / 64; j++) {
        int c = lane + j * 64;
        if (c < COUT) {
            float v = h[(size_t)wid * COUT + c];
            p1 = fmaf(v, as[c], p1);
            p2 = fmaf(v, ad[c], p2);
        }
    }
#pragma unroll
    for (int off = 32; off >= 1; off >>= 1) {
        p1 += __shfl_xor(p1, off);
        p2 += __shfl_xor(p2, off);
    }
    if (lane == 0) { es[wid] = p1; ed[wid] = p2; }
}

// ---------------- edge softmax: alpha[slot] for each CSR slot ----------------
// EXACT round-7 3-pass version (proven passing, absmax 2^-16). Do not restructure:
// the round-10 single-pass rewrite deterministically shifted output by 13 ulp.

__global__ __launch_bounds__(256) void k_alpha(const float* __restrict__ es, const float* __restrict__ ed,
                                               const int* __restrict__ rowstart, const int* __restrict__ csr,
                                               float* __restrict__ alpha, int n) {
    int wid = (blockIdx.x * 256 + threadIdx.x) >> 6;
    int lane = threadIdx.x & 63;
    if (wid >= n) return;
    int e0 = rowstart[wid], e1 = rowstart[wid + 1];
    float edv = ed[wid];
    float m = -1e30f;
    for (int s = e0 + lane; s < e1; s += 64) {
        float ev = es[csr[s]] + edv;
        ev = (ev > 0.f) ? ev : ev * LRELU_SLOPE;
        m = fmaxf(m, ev);
    }
#pragma unroll
    for (int off = 32; off >= 1; off >>= 1) m = fmaxf(m, __shfl_xor(m, off));
    float sum = 0.f;
    for (int s = e0 + lane; s < e1; s += 64) {
        float ev = es[csr[s]] + edv;
        ev = (ev > 0.f) ? ev : ev * LRELU_SLOPE;
        sum += expf(ev - m);
    }
#pragma unroll
    for (int off = 32; off >= 1; off >>= 1) sum += __shfl_xor(sum, off);
    float inv = 1.f / sum;  // self loop guarantees sum > 0
    for (int s = e0 + lane; s < e1; s += 64) {
        float ev = es[csr[s]] + edv;
        ev = (ev > 0.f) ? ev : ev * LRELU_SLOPE;
        alpha[s] = expf(ev - m) * inv;
    }
}

// ---------------- weighted gather: out[d] = relu(sum_e alpha[e]*h[src[e]] + bias) ----------------
// wave per dst. deg<=64 fast path: edge list staged in registers, WAVE-UNIFORM loop
// (all lanes run ceil(deg/NG) iterations; tail masked with a=0, shuffle source clamped)
// so no __shfl executes under divergence. Per-lane fmaf chain and reduce tree are
// bit-identical to the round-7 streaming version.

template <int COUT>
__global__ __launch_bounds__(256) void k_gather(const float* __restrict__ h, const float* __restrict__ alpha,
                                                const int* __restrict__ rowstart, const int* __restrict__ csr,
                                                const float* __restrict__ bias, float* __restrict__ out, int n) {
    constexpr int GSZ = COUT / 4;   // lanes per edge
    constexpr int NG = 64 / GSZ;    // edges per iteration
    int wid = (blockIdx.x * 256 + threadIdx.x) >> 6;
    int lane = threadIdx.x & 63;
    if (wid >= n) return;
    int e0 = rowstart[wid], e1 = rowstart[wid + 1];
    int deg = e1 - e0;
    int g = lane / GSZ;
    int li = lane % GSZ;
    float acc0 = 0.f, acc1 = 0.f, acc2 = 0.f, acc3 = 0.f;

    if (deg <= 64) {
        // stage edge list in registers: one coalesced load per wave
        int csrv = 0;
        float av = 0.f;
        if (lane < deg) {
            csrv = csr[e0 + lane];
            av = alpha[e0 + lane];
        }
        const int kend = ((deg + NG - 1) / NG) * NG;  // uniform trip count for all lanes
        for (int k = g; k < kend; k += NG) {
            bool valid = (k < deg);
            int kk = valid ? k : 0;
            int srcn = __shfl(csrv, kk);
            float a = __shfl(av, kk);
            a = valid ? a : 0.f;                      // fmaf(0,v,acc) == acc
            float4 v = *(const float4*)&h[(size_t)srcn * COUT + li * 4];
            acc0 = fmaf(a, v.x, acc0);
            acc1 = fmaf(a, v.y, acc1);
            acc2 = fmaf(a, v.z, acc2);
            acc3 = fmaf(a, v.w, acc3);
        }
    } else {
        // fallback streaming loop (not expected at this degree distribution)
        for (int base = e0; base < e1; base += NG) {
            int slot = base + g;
            if (slot < e1) {
                int srcn = csr[slot];
                float a = alpha[slot];
                float4 v = *(const float4*)&h[(size_t)srcn * COUT + li * 4];
                acc0 = fmaf(a, v.x, acc0);
                acc1 = fmaf(a, v.y, acc1);
                acc2 = fmaf(a, v.z, acc2);
                acc3 = fmaf(a, v.w, acc3);
            }
        }
    }
#pragma unroll
    for (int off = GSZ; off < 64; off <<= 1) {
        acc0 += __shfl_xor(acc0, off);
        acc1 += __shfl_xor(acc1, off);
        acc2 += __shfl_xor(acc2, off);
        acc3 += __shfl_xor(acc3, off);
    }
    if (lane < GSZ) {
        float4 bv = *(const float4*)&bias[lane * 4];
        float4 o;
        o.x = fmaxf(acc0 + bv.x, 0.f);
        o.y = fmaxf(acc1 + bv.y, 0.f);
        o.z = fmaxf(acc2 + bv.z, 0.f);
        o.w = fmaxf(acc3 + bv.w, 0.f);
        *(float4*)&out[(size_t)wid * COUT + lane * 4] = o;
    }
}

// ---------------- final FC: out[n,40] = h[n,128] @ fcW[128,40] + fcb ----------------

__global__ __launch_bounds__(256) void k_fc(const float* __restrict__ h, const float* __restrict__ W,
                                            const float* __restrict__ bias, float* __restrict__ out, int n) {
    __shared__ float Wl[128 * 40];
    for (int i = threadIdx.x; i < 128 * 40; i += 256) Wl[i] = W[i];
    __syncthreads();
    int idx = blockIdx.x * 256 + threadIdx.x;
    if (idx >= n * 40) return;
    int row = idx / 40;
    int col = idx % 40;
    float acc = 0.f;
#pragma unroll 8
    for (int k = 0; k < 128; k++) acc = fmaf(h[(size_t)row * 128 + k], Wl[k * 40 + col], acc);
    out[idx] = acc + bias[col];
}

// ---------------- launch ----------------

extern "C" void kernel_launch(void* const* d_in, const int* in_sizes, int n_in,
                              void* d_out, int out_size, void* d_ws, size_t ws_size,
                              hipStream_t stream) {
    const float* x   = (const float*)d_in[0];
    const int*   ei  = (const int*)d_in[1];
    const float* W1  = (const float*)d_in[2];
    const float* a1s = (const float*)d_in[3];
    const float* a1d = (const float*)d_in[4];
    const float* b1  = (const float*)d_in[5];
    const float* W2  = (const float*)d_in[6];
    const float* a2s = (const float*)d_in[7];
    const float* a2d = (const float*)d_in[8];
    const float* b2  = (const float*)d_in[9];
    const float* W3  = (const float*)d_in[10];
    const float* a3s = (const float*)d_in[11];
    const float* a3d = (const float*)d_in[12];
    const float* b3  = (const float*)d_in[13];
    const float* W4  = (const float*)d_in[14];
    const float* a4s = (const float*)d_in[15];
    const float* a4d = (const float*)d_in[16];
    const float* b4  = (const float*)d_in[17];
    const float* fcW = (const float*)d_in[18];
    const float* fcb = (const float*)d_in[19];

    const int n = in_sizes[0] / 256;   // 50000
    const int E = in_sizes[1] / 2;     // 800000
    const int* src = ei;
    const int* dst = ei + E;

    char* p = (char*)d_ws;
    auto alloc = [&](size_t bytes) -> char* {
        char* r = p;
        p += (bytes + 255) & ~(size_t)255;
        return r;
    };
    int*   deg      = (int*)alloc((size_t)n * 4);
    int*   cursor   = (int*)alloc((size_t)n * 4);
    int*   rowstart = (int*)alloc((size_t)(n + 1) * 4);
    int*   incl     = (int*)alloc((size_t)n * 4);
    int*   partials = (int*)alloc(256 * 4);
    int*   csr      = (int*)alloc((size_t)(E + n) * 4);
    float* alpha    = (float*)alloc((size_t)(E + n) * 4);
    float* es       = (float*)alloc((size_t)n * 4);
    float* ed       = (float*)alloc((size_t)n * 4);
    float* hA       = (float*)alloc((size_t)n * 128 * 4);
    float* hB       = (float*)alloc((size_t)n * 128 * 4);

    const int nb = (n + 1023) / 1024;

    k_init_deg<<<(n + 255) / 256, 256, 0, stream>>>(deg, n);
    k_count<<<(E + 255) / 256, 256, 0, stream>>>(dst, E, deg);
    k_scan1<<<nb, 1024, 0, stream>>>(deg, n, incl, partials);
    k_scan2<<<1, 64, 0, stream>>>(partials, nb);
    k_scan3<<<nb, 1024, 0, stream>>>(incl, partials, n, rowstart);
    k_fill_self<<<(n + 255) / 256, 256, 0, stream>>>(rowstart, n, csr, cursor);
    k_fill<<<(E + 255) / 256, 256, 0, stream>>>(src, dst, E, rowstart, cursor, csr);

    const int gw = (n + 3) / 4;  // blocks for wave-per-node kernels

    // layer 1: 256 -> 32
    k_gemm_tiled<256, 32, 128, 4, 4><<<(n + 127) / 128, 256, 0, stream>>>(x, W1, hA, n);
    k_attn<32><<<gw, 256, 0, stream>>>(hA, a1s, a1d, es, ed, n);
    k_alpha<<<gw, 256, 0, stream>>>(es, ed, rowstart, csr, alpha, n);
    k_gather<32><<<gw, 256, 0, stream>>>(hA, alpha, rowstart, csr, b1, hB, n);
    // layer 2: 32 -> 64
    k_gemm_tiled<32, 64, 64, 4, 4><<<(n + 63) / 64, 256, 0, stream>>>(hB, W2, hA, n);
    k_attn<64><<<gw, 256, 0, stream>>>(hA, a2s, a2d, es, ed, n);
    k_alpha<<<gw, 256, 0, stream>>>(es, ed, rowstart, csr, alpha, n);
    k_gather<64><<<gw, 256, 0, stream>>>(hA, alpha, rowstart, csr, b2, hB, n);
    // layer 3: 64 -> 128
    k_gemm_tiled<64, 128, 64, 4, 8><<<(n + 63) / 64, 256, 0, stream>>>(hB, W3, hA, n);
    k_attn<128><<<gw, 256, 0, stream>>>(hA, a3s, a3d, es, ed, n);
    k_alpha<<<gw, 256, 0, stream>>>(es, ed, rowstart, csr, alpha, n);
    k_gather<128><<<gw, 256, 0, stream>>>(hA, alpha, rowstart, csr, b3, hB, n);
    // layer 4: 128 -> 128
    k_gemm_tiled<128, 128, 64, 4, 8><<<(n + 63) / 64, 256, 0, stream>>>(hB, W4, hA, n);
    k_attn<128><<<gw, 256, 0, stream>>>(hA, a4s, a4d, es, ed, n);
    k_alpha<<<gw, 256, 0, stream>>>(es, ed, rowstart, csr, alpha, n);
    k_gather<128><<<gw, 256, 0, stream>>>(hA, alpha, rowstart, csr, b4, hB, n);
    // final FC: 128 -> 40
    k_fc<<<((size_t)n * 40 + 255) / 256, 256, 0, stream>>>(hB, fcW, fcb, (float*)d_out, n);
}

// Round 16
// 559.070 us; speedup vs baseline: 1.6929x; 1.1171x over previous
//
#include <hip/hip_runtime.h>
#include <math.h>

#define LRELU_SLOPE 0.2f

// ---------------- CSR build ----------------

__global__ __launch_bounds__(256) void k_init_deg(int* __restrict__ deg, int n) {
    int i = blockIdx.x * 256 + threadIdx.x;
    if (i < n) deg[i] = 1;  // self loop contributes 1
}

__global__ __launch_bounds__(256) void k_count(const int* __restrict__ dst, int E, int* __restrict__ deg) {
    int i = blockIdx.x * 256 + threadIdx.x;
    if (i < E) atomicAdd(&deg[dst[i]], 1);
}

__global__ __launch_bounds__(1024) void k_scan1(const int* __restrict__ deg, int n,
                                                int* __restrict__ incl, int* __restrict__ partials) {
    __shared__ int tmp[1024];
    int i = blockIdx.x * 1024 + threadIdx.x;
    tmp[threadIdx.x] = (i < n) ? deg[i] : 0;
    __syncthreads();
    for (int off = 1; off < 1024; off <<= 1) {
        int t = (threadIdx.x >= off) ? tmp[threadIdx.x - off] : 0;
        __syncthreads();
        tmp[threadIdx.x] += t;
        __syncthreads();
    }
    if (i < n) incl[i] = tmp[threadIdx.x];
    if (threadIdx.x == 1023) partials[blockIdx.x] = tmp[1023];
}

__global__ void k_scan2(int* __restrict__ partials, int nb) {
    if (threadIdx.x == 0 && blockIdx.x == 0) {
        int run = 0;
        for (int i = 0; i < nb; i++) { int v = partials[i]; partials[i] = run; run += v; }
    }
}

__global__ __launch_bounds__(1024) void k_scan3(const int* __restrict__ incl, const int* __restrict__ partials,
                                                int n, int* __restrict__ rowstart) {
    int i = blockIdx.x * 1024 + threadIdx.x;
    if (i < n) rowstart[i + 1] = incl[i] + partials[blockIdx.x];
    if (i == 0) rowstart[0] = 0;
}

__global__ __launch_bounds__(256) void k_fill_self(const int* __restrict__ rowstart, int n,
                                                   int* __restrict__ csr, int* __restrict__ cursor) {
    int i = blockIdx.x * 256 + threadIdx.x;
    if (i < n) { csr[rowstart[i]] = i; cursor[i] = 1; }
}

__global__ __launch_bounds__(256) void k_fill(const int* __restrict__ src, const int* __restrict__ dst, int E,
                                              const int* __restrict__ rowstart, int* __restrict__ cursor,
                                              int* __restrict__ csr) {
    int i = blockIdx.x * 256 + threadIdx.x;
    if (i < E) {
        int d = dst[i];
        int p = rowstart[d] + atomicAdd(&cursor[d], 1);
        csr[p] = src[i];
    }
}

// ---------------- register-tiled GEMM: out[n,COUT] = in[n,CIN] @ W[CIN,COUT] ----------------

template <int CIN, int COUT, int MT, int TM, int TN>
__global__ __launch_bounds__(256) void k_gemm_tiled(const float* __restrict__ in, const float* __restrict__ W,
                                                    float* __restrict__ out, int n) {
    constexpr int KB = 32;
    constexpr int NCT = COUT / TN;
    constexpr int NRT = MT / TM;
    static_assert(NCT * NRT == 256, "thread tiling must cover 256 threads");
    static_assert(CIN % KB == 0, "K must be multiple of KB");
    __shared__ __align__(16) float Xl[KB][MT + 4];
    __shared__ __align__(16) float Wl[KB][COUT];

    const int tid = threadIdx.x;
    const int tcol = tid % NCT;
    const int trow = tid / NCT;
    const int row0 = blockIdx.x * MT;

    float acc[TM][TN];
#pragma unroll
    for (int i = 0; i < TM; i++)
#pragma unroll
        for (int j = 0; j < TN; j++) acc[i][j] = 0.f;

    for (int k0 = 0; k0 < CIN; k0 += KB) {
        constexpr int F4PT = MT * KB / 4 / 256;
#pragma unroll
        for (int it = 0; it < F4PT; ++it) {
            int idx = tid + it * 256;
            int r = idx / (KB / 4);
            int c4 = idx % (KB / 4);
            float4 v = make_float4(0.f, 0.f, 0.f, 0.f);
            int gr = row0 + r;
            if (gr < n) v = *(const float4*)&in[(size_t)gr * CIN + k0 + c4 * 4];
            Xl[c4 * 4 + 0][r] = v.x;
            Xl[c4 * 4 + 1][r] = v.y;
            Xl[c4 * 4 + 2][r] = v.z;
            Xl[c4 * 4 + 3][r] = v.w;
        }
        constexpr int WF4 = KB * COUT / 4;
#pragma unroll
        for (int idx = tid; idx < WF4; idx += 256) {
            ((float4*)&Wl[0][0])[idx] = ((const float4*)&W[(size_t)k0 * COUT])[idx];
        }
        __syncthreads();

#pragma unroll
        for (int kk = 0; kk < KB; ++kk) {
            float xf[TM], wf[TN];
#pragma unroll
            for (int i = 0; i < TM; i += 4) {
                float4 v = *(const float4*)&Xl[kk][trow * TM + i];
                xf[i] = v.x; xf[i + 1] = v.y; xf[i + 2] = v.z; xf[i + 3] = v.w;
            }
#pragma unroll
            for (int j = 0; j < TN; j += 4) {
                float4 v = *(const float4*)&Wl[kk][tcol * TN + j];
                wf[j] = v.x; wf[j + 1] = v.y; wf[j + 2] = v.z; wf[j + 3] = v.w;
            }
#pragma unroll
            for (int i = 0; i < TM; i++)
#pragma unroll
                for (int j = 0; j < TN; j++) acc[i][j] = fmaf(xf[i], wf[j], acc[i][j]);
        }
        __syncthreads();
    }

#pragma unroll
    for (int i = 0; i < TM; i++) {
        int gr = row0 + trow * TM + i;
        if (gr < n) {
#pragma unroll
            for (int j = 0; j < TN; j += 4) {
                float4 v = make_float4(acc[i][j], acc[i][j + 1], acc[i][j + 2], acc[i][j + 3]);
                *(float4*)&out[(size_t)gr * COUT + tcol * TN + j] = v;
            }
        }
    }
}

// ---------------- attention coefficients: es = h @ a_s, ed = h @ a_d ----------------

template <int COUT>
__global__ __launch_bounds__(256) void k_attn(const float* __restrict__ h, const float* __restrict__ as,
                                              const float* __restrict__ ad, float* __restrict__ es,
                                              float* __restrict__ ed, int n) {
    int wid = (blockIdx.x * 256 + threadIdx.x) >> 6;
    int lane = threadIdx.x & 63;
    if (wid >= n) return;
    float p1 = 0.f, p2 = 0.f;
#pragma unroll
    for (int j = 0; j < (COUT + 63) / 64; j++) {
        int c = lane + j * 64;
        if (c < COUT) {
            float v = h[(size_t)wid * COUT + c];
            p1 = fmaf(v, as[c], p1);
            p2 = fmaf(v, ad[c], p2);
        }
    }
#pragma unroll
    for (int off = 32; off >= 1; off >>= 1) {
        p1 += __shfl_xor(p1, off);
        p2 += __shfl_xor(p2, off);
    }
    if (lane == 0) { es[wid] = p1; ed[wid] = p2; }
}

// ---------------- fused edge-softmax + weighted gather ----------------
// out[d] = relu(sum_e softmax(e)*h[src[e]] + bias), one wave per dst.
// deg<=64 fast path: edge list + e-values staged in registers; softmax computed
// in-register with the EXACT butterfly sequences of the proven 3-pass k_alpha
// (bit-identical alpha values: same ev per lane, same fmaxf/add shuffle order,
// inactive lanes contribute -1e30/0 exactly as the strided loops did).
// Gather loop is the round-15 proven WAVE-UNIFORM loop (no divergent __shfl —
// round-10's 13-ulp failure traced to shuffles under divergence).

template <int COUT>
__global__ __launch_bounds__(256) void k_agg(const float* __restrict__ h, const float* __restrict__ es,
                                             const float* __restrict__ ed, const int* __restrict__ rowstart,
                                             const int* __restrict__ csr, const float* __restrict__ bias,
                                             float* __restrict__ out, int n) {
    constexpr int GSZ = COUT / 4;   // lanes per edge
    constexpr int NG = 64 / GSZ;    // edges per iteration
    int wid = (blockIdx.x * 256 + threadIdx.x) >> 6;
    int lane = threadIdx.x & 63;
    if (wid >= n) return;
    int e0 = rowstart[wid], e1 = rowstart[wid + 1];
    int deg = e1 - e0;
    int g = lane / GSZ;
    int li = lane % GSZ;
    float acc0 = 0.f, acc1 = 0.f, acc2 = 0.f, acc3 = 0.f;
    float edv = ed[wid];

    if (deg <= 64) {
        // ---- stage edge list + e-value in registers (one coalesced pass) ----
        int csrv = 0;
        float ev = -1e30f;
        if (lane < deg) {
            csrv = csr[e0 + lane];
            float e = es[csrv] + edv;
            ev = (e > 0.f) ? e : e * LRELU_SLOPE;
        }
        // ---- in-register softmax (butterflies identical to proven k_alpha) ----
        float m = ev;
#pragma unroll
        for (int off = 32; off >= 1; off >>= 1) m = fmaxf(m, __shfl_xor(m, off));
        float ex = (lane < deg) ? expf(ev - m) : 0.f;
        float sum = ex;
#pragma unroll
        for (int off = 32; off >= 1; off >>= 1) sum += __shfl_xor(sum, off);
        float inv = 1.f / sum;  // self loop guarantees sum > 0
        float av = ex * inv;    // inactive lanes: ex=0 -> av=0
        // ---- wave-uniform gather loop (round-15 proven) ----
        const int kend = ((deg + NG - 1) / NG) * NG;
        for (int k = g; k < kend; k += NG) {
            bool valid = (k < deg);
            int kk = valid ? k : 0;
            int srcn = __shfl(csrv, kk);
            float a = __shfl(av, kk);
            a = valid ? a : 0.f;                      // fmaf(0,v,acc) == acc
            float4 v = *(const float4*)&h[(size_t)srcn * COUT + li * 4];
            acc0 = fmaf(a, v.x, acc0);
            acc1 = fmaf(a, v.y, acc1);
            acc2 = fmaf(a, v.z, acc2);
            acc3 = fmaf(a, v.w, acc3);
        }
    } else {
        // ---- streaming fallback with inline alpha (bit-identical 3-pass math;
        //      not expected at this degree distribution) ----
        float m = -1e30f;
        for (int s = e0 + lane; s < e1; s += 64) {
            float e = es[csr[s]] + edv;
            e = (e > 0.f) ? e : e * LRELU_SLOPE;
            m = fmaxf(m, e);
        }
#pragma unroll
        for (int off = 32; off >= 1; off >>= 1) m = fmaxf(m, __shfl_xor(m, off));
        float sum = 0.f;
        for (int s = e0 + lane; s < e1; s += 64) {
            float e = es[csr[s]] + edv;
            e = (e > 0.f) ? e : e * LRELU_SLOPE;
            sum += expf(e - m);
        }
#pragma unroll
        for (int off = 32; off >= 1; off >>= 1) sum += __shfl_xor(sum, off);
        float inv = 1.f / sum;
        for (int base = e0; base < e1; base += NG) {
            int slot = base + g;
            if (slot < e1) {
                int srcn = csr[slot];
                float e = es[srcn] + edv;
                e = (e > 0.f) ? e : e * LRELU_SLOPE;
                float a = expf(e - m) * inv;
                float4 v = *(const float4*)&h[(size_t)srcn * COUT + li * 4];
                acc0 = fmaf(a, v.x, acc0);
                acc1 = fmaf(a, v.y, acc1);
                acc2 = fmaf(a, v.z, acc2);
                acc3 = fmaf(a, v.w, acc3);
            }
        }
    }
#pragma unroll
    for (int off = GSZ; off < 64; off <<= 1) {
        acc0 += __shfl_xor(acc0, off);
        acc1 += __shfl_xor(acc1, off);
        acc2 += __shfl_xor(acc2, off);
        acc3 += __shfl_xor(acc3, off);
    }
    if (lane < GSZ) {
        float4 bv = *(const float4*)&bias[lane * 4];
        float4 o;
        o.x = fmaxf(acc0 + bv.x, 0.f);
        o.y = fmaxf(acc1 + bv.y, 0.f);
        o.z = fmaxf(acc2 + bv.z, 0.f);
        o.w = fmaxf(acc3 + bv.w, 0.f);
        *(float4*)&out[(size_t)wid * COUT + lane * 4] = o;
    }
}

// ---------------- final FC: out[n,40] = h[n,128] @ fcW[128,40] + fcb ----------------

__global__ __launch_bounds__(256) void k_fc(const float* __restrict__ h, const float* __restrict__ W,
                                            const float* __restrict__ bias, float* __restrict__ out, int n) {
    __shared__ float Wl[128 * 40];
    for (int i = threadIdx.x; i < 128 * 40; i += 256) Wl[i] = W[i];
    __syncthreads();
    int idx = blockIdx.x * 256 + threadIdx.x;
    if (idx >= n * 40) return;
    int row = idx / 40;
    int col = idx % 40;
    float acc = 0.f;
#pragma unroll 8
    for (int k = 0; k < 128; k++) acc = fmaf(h[(size_t)row * 128 + k], Wl[k * 40 + col], acc);
    out[idx] = acc + bias[col];
}

// ---------------- launch ----------------

extern "C" void kernel_launch(void* const* d_in, const int* in_sizes, int n_in,
                              void* d_out, int out_size, void* d_ws, size_t ws_size,
                              hipStream_t stream) {
    const float* x   = (const float*)d_in[0];
    const int*   ei  = (const int*)d_in[1];
    const float* W1  = (const float*)d_in[2];
    const float* a1s = (const float*)d_in[3];
    const float* a1d = (const float*)d_in[4];
    const float* b1  = (const float*)d_in[5];
    const float* W2  = (const float*)d_in[6];
    const float* a2s = (const float*)d_in[7];
    const float* a2d = (const float*)d_in[8];
    const float* b2  = (const float*)d_in[9];
    const float* W3  = (const float*)d_in[10];
    const float* a3s = (const float*)d_in[11];
    const float* a3d = (const float*)d_in[12];
    const float* b3  = (const float*)d_in[13];
    const float* W4  = (const float*)d_in[14];
    const float* a4s = (const float*)d_in[15];
    const float* a4d = (const float*)d_in[16];
    const float* b4  = (const float*)d_in[17];
    const float* fcW = (const float*)d_in[18];
    const float* fcb = (const float*)d_in[19];

    const int n = in_sizes[0] / 256;   // 50000
    const int E = in_sizes[1] / 2;     // 800000
    const int* src = ei;
    const int* dst = ei + E;

    char* p = (char*)d_ws;
    auto alloc = [&](size_t bytes) -> char* {
        char* r = p;
        p += (bytes + 255) & ~(size_t)255;
        return r;
    };
    int*   deg      = (int*)alloc((size_t)n * 4);
    int*   cursor   = (int*)alloc((size_t)n * 4);
    int*   rowstart = (int*)alloc((size_t)(n + 1) * 4);
    int*   incl     = (int*)alloc((size_t)n * 4);
    int*   partials = (int*)alloc(256 * 4);
    int*   csr      = (int*)alloc((size_t)(E + n) * 4);
    float* es       = (float*)alloc((size_t)n * 4);
    float* ed       = (float*)alloc((size_t)n * 4);
    float* hA       = (float*)alloc((size_t)n * 128 * 4);
    float* hB       = (float*)alloc((size_t)n * 128 * 4);

    const int nb = (n + 1023) / 1024;

    k_init_deg<<<(n + 255) / 256, 256, 0, stream>>>(deg, n);
    k_count<<<(E + 255) / 256, 256, 0, stream>>>(dst, E, deg);
    k_scan1<<<nb, 1024, 0, stream>>>(deg, n, incl, partials);
    k_scan2<<<1, 64, 0, stream>>>(partials, nb);
    k_scan3<<<nb, 1024, 0, stream>>>(incl, partials, n, rowstart);
    k_fill_self<<<(n + 255) / 256, 256, 0, stream>>>(rowstart, n, csr, cursor);
    k_fill<<<(E + 255) / 256, 256, 0, stream>>>(src, dst, E, rowstart, cursor, csr);

    const int gw = (n + 3) / 4;  // blocks for wave-per-node kernels

    // layer 1: 256 -> 32
    k_gemm_tiled<256, 32, 128, 4, 4><<<(n + 127) / 128, 256, 0, stream>>>(x, W1, hA, n);
    k_attn<32><<<gw, 256, 0, stream>>>(hA, a1s, a1d, es, ed, n);
    k_agg<32><<<gw, 256, 0, stream>>>(hA, es, ed, rowstart, csr, b1, hB, n);
    // layer 2: 32 -> 64
    k_gemm_tiled<32, 64, 64, 4, 4><<<(n + 63) / 64, 256, 0, stream>>>(hB, W2, hA, n);
    k_attn<64><<<gw, 256, 0, stream>>>(hA, a2s, a2d, es, ed, n);
    k_agg<64><<<gw, 256, 0, stream>>>(hA, es, ed, rowstart, csr, b2, hB, n);
    // layer 3: 64 -> 128
    k_gemm_tiled<64, 128, 64, 4, 8><<<(n + 63) / 64, 256, 0, stream>>>(hB, W3, hA, n);
    k_attn<128><<<gw, 256, 0, stream>>>(hA, a3s, a3d, es, ed, n);
    k_agg<128><<<gw, 256, 0, stream>>>(hA, es, ed, rowstart, csr, b3, hB, n);
    // layer 4: 128 -> 128
    k_gemm_tiled<128, 128, 64, 4, 8><<<(n + 63) / 64, 256, 0, stream>>>(hB, W4, hA, n);
    k_attn<128><<<gw, 256, 0, stream>>>(hA, a4s, a4d, es, ed, n);
    k_agg<128><<<gw, 256, 0, stream>>>(hA, es, ed, rowstart, csr, b4, hB, n);
    // final FC: 128 -> 40
    k_fc<<<((size_t)n * 40 + 255) / 256, 256, 0, stream>>>(hB, fcW, fcb, (float*)d_out, n);
}